// Round 6
// baseline (841.531 us; speedup 1.0000x reference)
//
#include <hip/hip_runtime.h>

// ---------------------------------------------------------------------------
// ShiftedWindowAttention (Swin block, no mask): B=32, H=W=56, C=384, ws=7,
// shift=3, heads=12, hd=32.
//   prep:      weights -> bf16 [n][k]; bias -> C-frag order (+mask);
//              x -> bf16 (XB, aliases AO region); m->window LUT
//   qkv_gemm:  XB @ Wq^T -> Q,K,V bf16 [win][head][49][32]
//   attn:      4 waves/block, 1 wave per (win,head)
//   proj_gemm: AO @ Wp^T + proj_b -> out fp32
// R4: global_load_lds width=16 staging, linear LDS tiles (172 us qkv).
// R5: 2-phase dbuf + LUT epilogue (null on time; VALU off critical path).
// R7: 256x128/512thr launch_bounds(512,6) -> VGPR spill catastrophe. REVERTED.
// R8: counted-vmcnt depth-2 at 128^2 -> NULL (loads complete in time; the
//     stall is the 2-barrier-per-K-step rendezvous itself).
// R9 (this round): GEMMs go LDS-FREE (flatmm style). Rationale: K=384 only;
//     A (XB) is read 9x per XCD and B (weights) 49x per XCD -> both L2/L3
//     resident (qkv FETCH 51MB << 278MB logical confirms). Each lane loads
//     its MFMA fragments directly global->reg via 8 base pointers + imm
//     offsets; full K unroll; ZERO barriers; waves fully independent.
//     VGPR kept ~<=128 (acc 64 + frags 32 + ptrs 16) for 4 waves/SIMD.
// ---------------------------------------------------------------------------

typedef __attribute__((ext_vector_type(8))) short short8;
typedef __attribute__((ext_vector_type(4))) float floatx4;

#define CDIM  384
#define QKVN  1152
#define MROWS 100352      // 32*3136
#define LROW  3136        // 56*56

static constexpr size_t QKV_ELEMS = 38535168ull;   // 2048*12*49*32
static constexpr size_t OFF_Q    = 0;
static constexpr size_t OFF_K    = OFF_Q  + QKV_ELEMS * 2 + 4096;
static constexpr size_t OFF_V    = OFF_K  + QKV_ELEMS * 2 + 4096;
static constexpr size_t OFF_AO   = OFF_V  + QKV_ELEMS * 2 + 4096;  // also XB (x as bf16) before attn runs
static constexpr size_t OFF_WQ   = OFF_AO + (size_t)MROWS * CDIM * 2 + 4096;
static constexpr size_t OFF_WP   = OFF_WQ + (size_t)QKVN * CDIM * 2 + 256;
static constexpr size_t OFF_BIAS = OFF_WP + (size_t)CDIM * CDIM * 2 + 256;
static constexpr size_t OFF_LUT  = OFF_BIAS + (size_t)12 * 64 * 64 * 4 + 256;

__device__ __forceinline__ unsigned short f2bf(float f) {
  unsigned int u = __float_as_uint(f);
  unsigned int lsb = (u >> 16) & 1u;
  u += 0x7fffu + lsb;
  return (unsigned short)(u >> 16);
}

// ---------------------------------------------------------------------------
// prep: weight transpose/convert + bias in C-frag order + x -> bf16 + LUT
// ---------------------------------------------------------------------------
__global__ __launch_bounds__(256) void prep_kernel(
    const float* __restrict__ x, const float* __restrict__ qkv_w,
    const float* __restrict__ proj_w, const float* __restrict__ rbt,
    char* __restrict__ ws) {
  unsigned short* Wq = (unsigned short*)(ws + OFF_WQ);
  unsigned short* Wp = (unsigned short*)(ws + OFF_WP);
  unsigned short* XB = (unsigned short*)(ws + OFF_AO);
  float* biasp = (float*)(ws + OFF_BIAS);
  int* lut = (int*)(ws + OFF_LUT);
  const int tid = blockIdx.x * blockDim.x + threadIdx.x;
  const int stride = gridDim.x * blockDim.x;
  for (int idx = tid; idx < QKVN * CDIM; idx += stride) {
    int n = idx / CDIM, k = idx - n * CDIM;
    Wq[idx] = f2bf(qkv_w[(size_t)k * QKVN + n]);
  }
  for (int idx = tid; idx < CDIM * CDIM; idx += stride) {
    int n = idx / CDIM, k = idx - n * CDIM;
    Wp[idx] = f2bf(proj_w[(size_t)k * CDIM + n]);
  }
  for (int idx = tid; idx < 12 * 64 * 64; idx += stride) {
    int h = idx / 4096;
    int rem = idx - h * 4096;
    int lane = rem / 64;
    int e = rem - lane * 64;        // (fm*4+fn)*4 + r
    int fm = e >> 4, fn = (e >> 2) & 3, r = e & 3;
    int row = fm * 16 + (lane >> 4) * 4 + r;
    int col = fn * 16 + (lane & 15);
    float v = -1e30f;
    if (row < 49 && col < 49) {
      int i = row / 7, j = row - i * 7;
      int k2 = col / 7, l2 = col - k2 * 7;
      int rpi = (i - k2 + 6) * 13 + (j - l2 + 6);
      v = rbt[rpi * 12 + h];
    }
    biasp[idx] = v;
  }
  // m -> scatter-base LUT: lut[m] = win*18816 + nidx*32
  for (int idx = tid; idx < MROWS; idx += stride) {
    int b_ = idx / LROW, l = idx - b_ * LROW;
    int y = l / 56, xx = l - y * 56;
    int yr = y + 53; if (yr >= 56) yr -= 56;   // roll -3
    int xr = xx + 53; if (xr >= 56) xr -= 56;
    int win = b_ * 64 + (yr / 7) * 8 + (xr / 7);
    int nidx = (yr % 7) * 7 + (xr % 7);
    lut[idx] = win * 18816 + nidx * 32;        // = ((win*12)*49 + nidx)*32
  }
  // x fp32 -> bf16, 8 elems/iter
  const size_t n8 = (size_t)MROWS * CDIM / 8;   // 4,816,896
  for (size_t idx = tid; idx < n8; idx += stride) {
    const float4* s = (const float4*)(x + idx * 8);
    float4 f0 = s[0], f1 = s[1];
    uint4 o;
    o.x = (unsigned)f2bf(f0.x) | ((unsigned)f2bf(f0.y) << 16);
    o.y = (unsigned)f2bf(f0.z) | ((unsigned)f2bf(f0.w) << 16);
    o.z = (unsigned)f2bf(f1.x) | ((unsigned)f2bf(f1.y) << 16);
    o.w = (unsigned)f2bf(f1.z) | ((unsigned)f2bf(f1.w) << 16);
    ((uint4*)XB)[idx] = o;
  }
}

// ---------------------------------------------------------------------------
// QKV GEMM, LDS-free: 100352x1152 = XB(bf16) @ Wq^T.  BM=128 BN=128 BK=32,
// 256 thr = 4 waves 2x2, per-wave 64x64 = 4x4 frags of 16x16x32 bf16.
// Fragments loaded straight from global (L2/L3-hot: XB 9x-reused, Wq
// 49x-reused per XCD via the swizzle).  8 base pointers, imm offsets,
// full K unroll, NO LDS, NO barriers -> waves fully independent.
// Linear grid 7056, swizzle: xcd=L%8, slot=L/8, m=(slot/9)*8+xcd, n=slot%9.
// Epilogue: +bias, Q*=1/sqrt(32), scatter via lut to [win][head][n][d] bf16.
// ---------------------------------------------------------------------------
__global__ __launch_bounds__(256) void qkv_gemm(
    const float* __restrict__ qkv_b, char* __restrict__ ws) {
  const unsigned short* XB = (const unsigned short*)(ws + OFF_AO);
  const unsigned short* Wq = (const unsigned short*)(ws + OFF_WQ);
  unsigned short* Qb = (unsigned short*)(ws + OFF_Q);
  unsigned short* Kb = (unsigned short*)(ws + OFF_K);
  unsigned short* Vb = (unsigned short*)(ws + OFF_V);
  const int* lut = (const int*)(ws + OFF_LUT);
  const int L = blockIdx.x;
  const int xcd = L & 7, slot = L >> 3;
  const int g9 = slot / 9;
  const int m0 = (g9 * 8 + xcd) * 128;
  const int n0 = (slot - g9 * 9) * 128;
  const int t = threadIdx.x;
  const int lane = t & 63, li = lane & 15, qd = lane >> 4;
  const int wv = t >> 6, wm = wv >> 1, wn = wv & 1;

  const unsigned short* ap[4];
  const unsigned short* bp[4];
#pragma unroll
  for (int f = 0; f < 4; f++) {
    ap[f] = XB + (size_t)(m0 + wm * 64 + f * 16 + li) * CDIM + qd * 8;
    bp[f] = Wq + (size_t)(n0 + wn * 64 + f * 16 + li) * CDIM + qd * 8;
  }

  floatx4 acc[4][4] = {};
#pragma unroll
  for (int kt = 0; kt < 12; ++kt) {
    short8 a[4], b[4];
#pragma unroll
    for (int f = 0; f < 4; f++) a[f] = *(const short8*)(ap[f] + kt * 32);
#pragma unroll
    for (int f = 0; f < 4; f++) b[f] = *(const short8*)(bp[f] + kt * 32);
#pragma unroll
    for (int i = 0; i < 4; i++)
#pragma unroll
      for (int j = 0; j < 4; j++)
        acc[i][j] = __builtin_amdgcn_mfma_f32_16x16x32_bf16(a[i], b[j], acc[i][j], 0, 0, 0);
  }

  // epilogue: each 128-wide N-tile lies entirely in one of Q/K/V (384 = 3*128)
  const int which = n0 / CDIM;
  unsigned short* dst = which == 0 ? Qb : (which == 1 ? Kb : Vb);
  const float mul = (which == 0) ? 0.17677669529663689f : 1.0f;
#pragma unroll
  for (int i = 0; i < 4; i++) {
    int lbase[4];
#pragma unroll
    for (int r = 0; r < 4; r++)
      lbase[r] = lut[m0 + wm * 64 + i * 16 + qd * 4 + r];
#pragma unroll
    for (int j = 0; j < 4; j++) {
      int c = n0 + wn * 64 + j * 16 + li;
      int cc = c - which * CDIM;
      int head = cc >> 5, d = cc & 31;
      int hd_off = head * 1568 + d;          // head*49*32 + d
      float bval = qkv_b[c];
#pragma unroll
      for (int r = 0; r < 4; r++) {
        size_t off = (size_t)(lbase[r] + hd_off);
        dst[off] = f2bf((acc[i][j][r] + bval) * mul);
      }
    }
  }
}

// ---------------------------------------------------------------------------
// Attention: 256 thr = 4 waves, wave wv handles head blockIdx.y*4+wv of
// window blockIdx.x.  Per-wave LDS region SMEM[wv]: first holds V transposed
// (Vt[d][row], stride 72, cols 49..63 zeroed), V frags -> regs via
// ds_read_b128, then region overwritten by P (stride-72).  Q/K loads issued
// first so HBM latency overlaps staging.  No __syncthreads.
// ---------------------------------------------------------------------------
__global__ __launch_bounds__(256) void attn_kernel(char* __restrict__ ws) {
  __shared__ unsigned short SMEM[4][64 * 72];
  const int win = blockIdx.x;
  const int t = threadIdx.x, wv = t >> 6, lane = t & 63;
  const int h = blockIdx.y * 4 + wv;
  const int li = lane & 15, qd = lane >> 4;
  unsigned short* Sm = &SMEM[wv][0];
  const size_t whoff = (size_t)(win * 12 + h) * 49 * 32;
  const unsigned short* Qb = (const unsigned short*)(ws + OFF_Q) + whoff;
  const unsigned short* Kb = (const unsigned short*)(ws + OFF_K) + whoff;
  const unsigned short* Vb = (const unsigned short*)(ws + OFF_V) + whoff;
  const float* biasp = (const float*)(ws + OFF_BIAS) + ((size_t)h * 64 + lane) * 64;

  // 1) issue Q/K fragment loads first (latency overlaps V staging below)
  short8 qa[4], kb4[4];
#pragma unroll
  for (int f = 0; f < 4; f++) {
    qa[f] = *(const short8*)(Qb + (f * 16 + li) * 32 + qd * 8);
    kb4[f] = *(const short8*)(Kb + (f * 16 + li) * 32 + qd * 8);
  }

  // 2) stage V transposed: Vt[d][row] at stride 72 (rows 0..31 of Sm).
  for (int idx = lane; idx < 512; idx += 64) {     // zero cols 48..63
    Sm[(idx >> 4) * 72 + 48 + (idx & 15)] = 0;
  }
  {
    const uint2* vsrc = (const uint2*)Vb;
    for (int idx = lane; idx < 392; idx += 64) {   // 49 rows * 8 chunks
      uint2 dv = vsrc[idx];
      int row = idx >> 3, d0 = (idx & 7) * 4;
      Sm[(d0 + 0) * 72 + row] = (unsigned short)(dv.x & 0xffff);
      Sm[(d0 + 1) * 72 + row] = (unsigned short)(dv.x >> 16);
      Sm[(d0 + 2) * 72 + row] = (unsigned short)(dv.y & 0xffff);
      Sm[(d0 + 3) * 72 + row] = (unsigned short)(dv.y >> 16);
    }
  }

  // 3) QK^T
  floatx4 s[4][4] = {};
#pragma unroll
  for (int i = 0; i < 4; i++)
#pragma unroll
    for (int j = 0; j < 4; j++)
      s[i][j] = __builtin_amdgcn_mfma_f32_16x16x32_bf16(qa[i], kb4[j], s[i][j], 0, 0, 0);

  // 4) V B-frags from Vt (before P overwrites the region)
  short8 vb[2][2];
#pragma unroll
  for (int ss = 0; ss < 2; ss++)
#pragma unroll
    for (int nf = 0; nf < 2; nf++)
      vb[ss][nf] = *(const short8*)&Sm[(nf * 16 + li) * 72 + ss * 32 + qd * 8];

  // 5) softmax numerator + row sums + P -> LDS (stride 72)
  float rsum[4][4];
#pragma unroll
  for (int fm = 0; fm < 4; fm++) {
#pragma unroll
    for (int fn = 0; fn < 4; fn++) {
      floatx4 bv = *(const floatx4*)(biasp + (fm * 4 + fn) * 4);
#pragma unroll
      for (int r = 0; r < 4; r++)
        s[fm][fn][r] = __expf(s[fm][fn][r] + bv[r]);
    }
#pragma unroll
    for (int r = 0; r < 4; r++) {
      float v = s[fm][0][r] + s[fm][1][r] + s[fm][2][r] + s[fm][3][r];
      v += __shfl_xor(v, 1);
      v += __shfl_xor(v, 2);
      v += __shfl_xor(v, 4);
      v += __shfl_xor(v, 8);
      rsum[fm][r] = v;
    }
#pragma unroll
    for (int fn = 0; fn < 4; fn++)
#pragma unroll
      for (int r = 0; r < 4; r++)
        Sm[(fm * 16 + qd * 4 + r) * 72 + fn * 16 + li] = f2bf(s[fm][fn][r]);
  }

  // 6) PV
  floatx4 o[4][2] = {};
#pragma unroll
  for (int fm = 0; fm < 4; fm++)
#pragma unroll
    for (int ss = 0; ss < 2; ss++) {
      short8 pa = *(const short8*)&Sm[(fm * 16 + li) * 72 + ss * 32 + qd * 8];
#pragma unroll
      for (int nf = 0; nf < 2; nf++)
        o[fm][nf] = __builtin_amdgcn_mfma_f32_16x16x32_bf16(pa, vb[ss][nf], o[fm][nf], 0, 0, 0);
    }

  // 7) normalize + scatter to AO (un-roll +3)
  unsigned short* AO = (unsigned short*)(ws + OFF_AO);
  const int b_ = win >> 6, wrem = win & 63, wy = wrem >> 3, wx = wrem & 7;
#pragma unroll
  for (int fm = 0; fm < 4; fm++)
#pragma unroll
    for (int r = 0; r < 4; r++) {
      int n = fm * 16 + qd * 4 + r;
      if (n >= 49) continue;
      float inv = 1.0f / rsum[fm][r];
      int i_ = n / 7, j_ = n - i_ * 7;
      int y = wy * 7 + i_ + 3;  if (y >= 56) y -= 56;
      int xx = wx * 7 + j_ + 3; if (xx >= 56) xx -= 56;
      size_t base = ((size_t)b_ * LROW + y * 56 + xx) * CDIM + h * 32;
#pragma unroll
      for (int nf = 0; nf < 2; nf++)
        AO[base + nf * 16 + li] = f2bf(o[fm][nf][r] * inv);
    }
}

// ---------------------------------------------------------------------------
// Proj GEMM, LDS-free: out(100352x384 fp32) = AO(bf16) @ Wp^T + proj_b.
// Same flat structure as qkv_gemm; grid 2352: m=(slot/3)*8+xcd, n=slot%3.
// ---------------------------------------------------------------------------
__global__ __launch_bounds__(256) void proj_gemm(
    const float* __restrict__ proj_b, char* __restrict__ ws,
    float* __restrict__ out) {
  const unsigned short* AO = (const unsigned short*)(ws + OFF_AO);
  const unsigned short* Wp = (const unsigned short*)(ws + OFF_WP);
  const int L = blockIdx.x;
  const int xcd = L & 7, slot = L >> 3;
  const int g3 = slot / 3;
  const int m0 = (g3 * 8 + xcd) * 128;
  const int n0 = (slot - g3 * 3) * 128;
  const int t = threadIdx.x;
  const int lane = t & 63, li = lane & 15, qd = lane >> 4;
  const int wv = t >> 6, wm = wv >> 1, wn = wv & 1;

  const unsigned short* ap[4];
  const unsigned short* bp[4];
#pragma unroll
  for (int f = 0; f < 4; f++) {
    ap[f] = AO + (size_t)(m0 + wm * 64 + f * 16 + li) * CDIM + qd * 8;
    bp[f] = Wp + (size_t)(n0 + wn * 64 + f * 16 + li) * CDIM + qd * 8;
  }

  floatx4 acc[4][4] = {};
#pragma unroll
  for (int kt = 0; kt < 12; ++kt) {
    short8 a[4], b[4];
#pragma unroll
    for (int f = 0; f < 4; f++) a[f] = *(const short8*)(ap[f] + kt * 32);
#pragma unroll
    for (int f = 0; f < 4; f++) b[f] = *(const short8*)(bp[f] + kt * 32);
#pragma unroll
    for (int i = 0; i < 4; i++)
#pragma unroll
      for (int j = 0; j < 4; j++)
        acc[i][j] = __builtin_amdgcn_mfma_f32_16x16x32_bf16(a[i], b[j], acc[i][j], 0, 0, 0);
  }

#pragma unroll
  for (int i = 0; i < 4; i++)
#pragma unroll
    for (int j = 0; j < 4; j++) {
      int c = n0 + wn * 64 + j * 16 + li;
      float bv = proj_b[c];
#pragma unroll
      for (int r = 0; r < 4; r++) {
        int m = m0 + wm * 64 + i * 16 + qd * 4 + r;
        out[(size_t)m * CDIM + c] = acc[i][j][r] + bv;
      }
    }
}

extern "C" void kernel_launch(void* const* d_in, const int* in_sizes, int n_in,
                              void* d_out, int out_size, void* d_ws, size_t ws_size,
                              hipStream_t stream) {
  const float* x      = (const float*)d_in[0];
  const float* qkv_w  = (const float*)d_in[1];
  const float* qkv_b  = (const float*)d_in[2];
  const float* proj_w = (const float*)d_in[3];
  const float* proj_b = (const float*)d_in[4];
  const float* rbt    = (const float*)d_in[5];
  char* ws = (char*)d_ws;
  float* out = (float*)d_out;

  prep_kernel<<<2048, 256, 0, stream>>>(x, qkv_w, proj_w, rbt, ws);
  qkv_gemm<<<7056, 256, 0, stream>>>(qkv_b, ws);
  attn_kernel<<<dim3(2048, 3), 256, 0, stream>>>(ws);
  proj_gemm<<<2352, 256, 0, stream>>>(proj_b, ws, out);
}

// Round 7
// 659.725 us; speedup vs baseline: 1.2756x; 1.2756x over previous
//
#include <hip/hip_runtime.h>

// ---------------------------------------------------------------------------
// ShiftedWindowAttention (Swin block, no mask): B=32, H=W=56, C=384, ws=7,
// shift=3, heads=12, hd=32.
//   prep:      weights -> bf16 [n][k]; bias -> C-frag order (+mask);
//              x -> bf16 (XB, aliases AO region)
//   qkv_gemm:  XB @ Wq^T -> QKVm[m][1152] bf16 (M-ROW-MAJOR, coalesced)
//   attn:      4 waves/block, 1 wave per (win,head); reads QKVm rows via
//              roll-mapping; V via LDS transpose; writes AO
//   proj_gemm: AO @ Wp^T + proj_b -> out fp32
// R4:  global_load_lds width=16 staging, linear LDS tiles (qkv 172 us).
// R5/R8: dbuf & counted-vmcnt both NULL -> not load/barrier bound.
// R7:  occupancy gamble -> spill disaster. R9: LDS-free -> 2x worse.
// R10 (this round): theory = qkv is bound by SCATTERED 2B WRITES (230 MB in
//     32B chunks, 64 scalar stores/thread, ~1.34 TB/s effective).  Fix: QKV
//     stored m-row-major via LDS-transpose epilogue -> coalesced 128B-chunk
//     dwordx4 stores.  The window scatter moves into attn's READS (L3-hot,
//     never the bottleneck).  attn row n>=49 reads map to valid in-bounds
//     image rows (finite), masked by bias cols / n>=49 row skip as before.
// ---------------------------------------------------------------------------

typedef __attribute__((ext_vector_type(8))) short short8;
typedef __attribute__((ext_vector_type(4))) float floatx4;

#define CDIM  384
#define QKVN  1152
#define MROWS 100352      // 32*3136
#define LROW  3136        // 56*56

static constexpr size_t QKV_ELEMS = 38535168ull;   // legacy sizing (2048*12*49*32)
static constexpr size_t OFF_Q    = 0;              // QKVm[m][1152] lives here
static constexpr size_t OFF_K    = OFF_Q  + QKV_ELEMS * 2 + 4096;  // (legacy, unused)
static constexpr size_t OFF_V    = OFF_K  + QKV_ELEMS * 2 + 4096;  // (legacy, unused)
static constexpr size_t OFF_AO   = OFF_V  + QKV_ELEMS * 2 + 4096;  // XB before attn, AO after
static constexpr size_t OFF_WQ   = OFF_AO + (size_t)MROWS * CDIM * 2 + 4096;
static constexpr size_t OFF_WP   = OFF_WQ + (size_t)QKVN * CDIM * 2 + 256;
static constexpr size_t OFF_BIAS = OFF_WP + (size_t)CDIM * CDIM * 2 + 256;
// QKVm needs MROWS*1152*2 = 231,211,008 B <= OFF_AO (231,223,296 B). OK.

__device__ __forceinline__ unsigned short f2bf(float f) {
  unsigned int u = __float_as_uint(f);
  unsigned int lsb = (u >> 16) & 1u;
  u += 0x7fffu + lsb;
  return (unsigned short)(u >> 16);
}

// direct global -> LDS async copy, 16B per lane. LDS dest must be
// wave-uniform base (+ lane*16 implicit); global src is per-lane.
__device__ __forceinline__ void gl2lds16(const void* g, void* l) {
  __builtin_amdgcn_global_load_lds(
      (const __attribute__((address_space(1))) unsigned int*)g,
      (__attribute__((address_space(3))) unsigned int*)l, 16, 0, 0);
}

// ---------------------------------------------------------------------------
// prep: weight transpose/convert + bias in C-frag order + x -> bf16
// ---------------------------------------------------------------------------
__global__ __launch_bounds__(256) void prep_kernel(
    const float* __restrict__ x, const float* __restrict__ qkv_w,
    const float* __restrict__ proj_w, const float* __restrict__ rbt,
    char* __restrict__ ws) {
  unsigned short* Wq = (unsigned short*)(ws + OFF_WQ);
  unsigned short* Wp = (unsigned short*)(ws + OFF_WP);
  unsigned short* XB = (unsigned short*)(ws + OFF_AO);
  float* biasp = (float*)(ws + OFF_BIAS);
  const int tid = blockIdx.x * blockDim.x + threadIdx.x;
  const int stride = gridDim.x * blockDim.x;
  for (int idx = tid; idx < QKVN * CDIM; idx += stride) {
    int n = idx / CDIM, k = idx - n * CDIM;
    Wq[idx] = f2bf(qkv_w[(size_t)k * QKVN + n]);
  }
  for (int idx = tid; idx < CDIM * CDIM; idx += stride) {
    int n = idx / CDIM, k = idx - n * CDIM;
    Wp[idx] = f2bf(proj_w[(size_t)k * CDIM + n]);
  }
  for (int idx = tid; idx < 12 * 64 * 64; idx += stride) {
    int h = idx / 4096;
    int rem = idx - h * 4096;
    int lane = rem / 64;
    int e = rem - lane * 64;        // (fm*4+fn)*4 + r
    int fm = e >> 4, fn = (e >> 2) & 3, r = e & 3;
    int row = fm * 16 + (lane >> 4) * 4 + r;
    int col = fn * 16 + (lane & 15);
    float v = -1e30f;
    if (row < 49 && col < 49) {
      int i = row / 7, j = row - i * 7;
      int k2 = col / 7, l2 = col - k2 * 7;
      int rpi = (i - k2 + 6) * 13 + (j - l2 + 6);
      v = rbt[rpi * 12 + h];
    }
    biasp[idx] = v;
  }
  // x fp32 -> bf16, 8 elems/iter
  const size_t n8 = (size_t)MROWS * CDIM / 8;   // 4,816,896
  for (size_t idx = tid; idx < n8; idx += stride) {
    const float4* s = (const float4*)(x + idx * 8);
    float4 f0 = s[0], f1 = s[1];
    uint4 o;
    o.x = (unsigned)f2bf(f0.x) | ((unsigned)f2bf(f0.y) << 16);
    o.y = (unsigned)f2bf(f0.z) | ((unsigned)f2bf(f0.w) << 16);
    o.z = (unsigned)f2bf(f1.x) | ((unsigned)f2bf(f1.y) << 16);
    o.w = (unsigned)f2bf(f1.z) | ((unsigned)f2bf(f1.w) << 16);
    ((uint4*)XB)[idx] = o;
  }
}

// ---------------------------------------------------------------------------
// QKV GEMM: QKVm(100352x1152 bf16, row-major) = XB(bf16) @ Wq^T.
// BM=128 BN=128 BK=32, 256 thr = 4 waves 2x2, per-wave 64x64 = 4x4 frags.
// R4 staging: global_load_lds w16, single buffer, __syncthreads x2/iter.
// Epilogue: +bias, Q-cols *= 1/sqrt(32), LDS-transpose -> coalesced
// dwordx4 row-major stores (two phases: wn==0 cols 0..63, wn==1 cols 64..127).
// Grid 7056, swizzle: xcd=L%8, slot=L/8, m=(slot/9)*8+xcd, n=slot%9.
// ---------------------------------------------------------------------------
__global__ __launch_bounds__(256) void qkv_gemm(
    const float* __restrict__ qkv_b, char* __restrict__ ws) {
  __shared__ unsigned short SMEM[8192];   // As=[0..4095], Bs=[4096..8191]; epilogue: [128][64]
  unsigned short (*As)[32] = (unsigned short (*)[32])(&SMEM[0]);
  unsigned short (*Bs)[32] = (unsigned short (*)[32])(&SMEM[4096]);
  const unsigned short* XB = (const unsigned short*)(ws + OFF_AO);
  const unsigned short* Wq = (const unsigned short*)(ws + OFF_WQ);
  unsigned short* QKVm = (unsigned short*)(ws + OFF_Q);
  const int L = blockIdx.x;
  const int xcd = L & 7, slot = L >> 3;
  const int g9 = slot / 9;
  const int m0 = (g9 * 8 + xcd) * 128;
  const int n0 = (slot - g9 * 9) * 128;
  const int t = threadIdx.x;
  const int lane = t & 63, li = lane & 15, qd = lane >> 4;
  const int wv = t >> 6, wm = wv >> 1, wn = wv & 1;
  const int ld_r = lane >> 2;          // 0..15
  const int ld_c = (lane & 3) * 8;     // shorts
  const unsigned short* agp = XB + (size_t)(m0 + wv * 32 + ld_r) * CDIM + ld_c;
  const unsigned short* bgp = Wq + (size_t)(n0 + wv * 32 + ld_r) * CDIM + ld_c;

  floatx4 acc[4][4] = {};
  for (int k0 = 0; k0 < CDIM; k0 += 32) {
    gl2lds16(agp + k0,             &As[wv * 32][0]);
    gl2lds16(agp + k0 + 16 * CDIM, &As[wv * 32 + 16][0]);
    gl2lds16(bgp + k0,             &Bs[wv * 32][0]);
    gl2lds16(bgp + k0 + 16 * CDIM, &Bs[wv * 32 + 16][0]);
    __syncthreads();
    short8 a[4], b[4];
#pragma unroll
    for (int f = 0; f < 4; f++)
      a[f] = *(const short8*)&As[wm * 64 + f * 16 + li][qd * 8];
#pragma unroll
    for (int f = 0; f < 4; f++)
      b[f] = *(const short8*)&Bs[wn * 64 + f * 16 + li][qd * 8];
#pragma unroll
    for (int i = 0; i < 4; i++)
#pragma unroll
      for (int j = 0; j < 4; j++)
        acc[i][j] = __builtin_amdgcn_mfma_f32_16x16x32_bf16(a[i], b[j], acc[i][j], 0, 0, 0);
    __syncthreads();
  }

  // epilogue: bias + scale, then LDS transpose -> coalesced row-major stores
  const float mul = (n0 < 384) ? 0.17677669529663689f : 1.0f;  // Q tiles 0..2
  float bvals[4];
#pragma unroll
  for (int j = 0; j < 4; j++)
    bvals[j] = qkv_b[n0 + wn * 64 + j * 16 + li];

#pragma unroll
  for (int half = 0; half < 2; half++) {
    if (wn == half) {
#pragma unroll
      for (int i = 0; i < 4; i++)
#pragma unroll
        for (int j = 0; j < 4; j++)
#pragma unroll
          for (int r = 0; r < 4; r++) {
            int row = wm * 64 + i * 16 + qd * 4 + r;
            int col = j * 16 + li;
            SMEM[row * 64 + col] = f2bf((acc[i][j][r] + bvals[j]) * mul);
          }
    }
    __syncthreads();
    // store 128 rows x 64 shorts: thread t -> row t>>1, 32-short half-row
    {
      int r = t >> 1;
      int c0 = (t & 1) * 32;
      const uint4* src = (const uint4*)&SMEM[r * 64 + c0];
      uint4* dst = (uint4*)(QKVm + (size_t)(m0 + r) * QKVN + n0 + half * 64 + c0);
      uint4 v0 = src[0], v1 = src[1], v2 = src[2], v3 = src[3];
      dst[0] = v0; dst[1] = v1; dst[2] = v2; dst[3] = v3;
    }
    __syncthreads();
  }
}

// ---------------------------------------------------------------------------
// Attention: 256 thr = 4 waves, wave wv handles head blockIdx.y*4+wv of
// window blockIdx.x.  QKVm[m][1152] rows located via the shift-roll mapping
// (same formula as the AO write).  Per-wave LDS SMEM[wv]: V transposed
// (Vt[d][row], stride 72, cols 48..63 zeroed then cols<49 filled), V frags
// via ds_read_b128; region then overwritten by P (stride 72).
// ---------------------------------------------------------------------------
__global__ __launch_bounds__(256) void attn_kernel(char* __restrict__ ws) {
  __shared__ unsigned short SMEM[4][64 * 72];
  const int win = blockIdx.x;
  const int t = threadIdx.x, wv = t >> 6, lane = t & 63;
  const int h = blockIdx.y * 4 + wv;
  const int li = lane & 15, qd = lane >> 4;
  unsigned short* Sm = &SMEM[wv][0];
  const unsigned short* QKVm = (const unsigned short*)(ws + OFF_Q);
  const float* biasp = (const float*)(ws + OFF_BIAS) + ((size_t)h * 64 + lane) * 64;
  const int b_ = win >> 6, wrem = win & 63, wy = wrem >> 3, wx = wrem & 7;
  const int qoff = h * 32, koff = 384 + h * 32, voff = 768 + h * 32;

  // row n of this window -> m index in the un-rolled image (+3 shift)
  auto msrc_of = [&](int n) -> int {
    int i_ = n / 7, j_ = n - i_ * 7;
    int y = wy * 7 + i_ + 3;  if (y >= 56) y -= 56;
    int xx = wx * 7 + j_ + 3; if (xx >= 56) xx -= 56;
    return b_ * LROW + y * 56 + xx;
  };

  // 1) Q/K fragment loads (row-mapped); rows n>=49 read valid other image
  //    rows (finite) -- masked later by bias cols / n>=49 row skip.
  short8 qa[4], kb4[4];
#pragma unroll
  for (int f = 0; f < 4; f++) {
    const unsigned short* rowp = QKVm + (size_t)msrc_of(f * 16 + li) * QKVN;
    qa[f]  = *(const short8*)(rowp + qoff + qd * 8);
    kb4[f] = *(const short8*)(rowp + koff + qd * 8);
  }

  // 2) stage V transposed: Vt[d][row], stride 72; zero cols 48..63 first
  for (int idx = lane; idx < 512; idx += 64)
    Sm[(idx >> 4) * 72 + 48 + (idx & 15)] = 0;
  for (int idx = lane; idx < 392; idx += 64) {     // 49 rows x 8 uint2-chunks
    int row = idx >> 3, d0 = (idx & 7) * 4;
    const unsigned short* rowp = QKVm + (size_t)msrc_of(row) * QKVN + voff;
    uint2 dv = *(const uint2*)(rowp + d0);
    Sm[(d0 + 0) * 72 + row] = (unsigned short)(dv.x & 0xffff);
    Sm[(d0 + 1) * 72 + row] = (unsigned short)(dv.x >> 16);
    Sm[(d0 + 2) * 72 + row] = (unsigned short)(dv.y & 0xffff);
    Sm[(d0 + 3) * 72 + row] = (unsigned short)(dv.y >> 16);
  }

  // 3) QK^T
  floatx4 s[4][4] = {};
#pragma unroll
  for (int i = 0; i < 4; i++)
#pragma unroll
    for (int j = 0; j < 4; j++)
      s[i][j] = __builtin_amdgcn_mfma_f32_16x16x32_bf16(qa[i], kb4[j], s[i][j], 0, 0, 0);

  // 4) V B-frags from Vt (before P overwrites the region)
  short8 vb[2][2];
#pragma unroll
  for (int ss = 0; ss < 2; ss++)
#pragma unroll
    for (int nf = 0; nf < 2; nf++)
      vb[ss][nf] = *(const short8*)&Sm[(nf * 16 + li) * 72 + ss * 32 + qd * 8];

  // 5) softmax numerator + row sums + P -> LDS (stride 72)
  float rsum[4][4];
#pragma unroll
  for (int fm = 0; fm < 4; fm++) {
#pragma unroll
    for (int fn = 0; fn < 4; fn++) {
      floatx4 bv = *(const floatx4*)(biasp + (fm * 4 + fn) * 4);
#pragma unroll
      for (int r = 0; r < 4; r++)
        s[fm][fn][r] = __expf(s[fm][fn][r] + bv[r]);
    }
#pragma unroll
    for (int r = 0; r < 4; r++) {
      float v = s[fm][0][r] + s[fm][1][r] + s[fm][2][r] + s[fm][3][r];
      v += __shfl_xor(v, 1);
      v += __shfl_xor(v, 2);
      v += __shfl_xor(v, 4);
      v += __shfl_xor(v, 8);
      rsum[fm][r] = v;
    }
#pragma unroll
    for (int fn = 0; fn < 4; fn++)
#pragma unroll
      for (int r = 0; r < 4; r++)
        Sm[(fm * 16 + qd * 4 + r) * 72 + fn * 16 + li] = f2bf(s[fm][fn][r]);
  }

  // 6) PV
  floatx4 o[4][2] = {};
#pragma unroll
  for (int fm = 0; fm < 4; fm++)
#pragma unroll
    for (int ss = 0; ss < 2; ss++) {
      short8 pa = *(const short8*)&Sm[(fm * 16 + li) * 72 + ss * 32 + qd * 8];
#pragma unroll
      for (int nf = 0; nf < 2; nf++)
        o[fm][nf] = __builtin_amdgcn_mfma_f32_16x16x32_bf16(pa, vb[ss][nf], o[fm][nf], 0, 0, 0);
    }

  // 7) normalize + scatter to AO (un-roll +3; same mapping as reads)
  unsigned short* AO = (unsigned short*)(ws + OFF_AO);
#pragma unroll
  for (int fm = 0; fm < 4; fm++)
#pragma unroll
    for (int r = 0; r < 4; r++) {
      int n = fm * 16 + qd * 4 + r;
      if (n >= 49) continue;
      float inv = 1.0f / rsum[fm][r];
      size_t base = (size_t)msrc_of(n) * CDIM + h * 32;
#pragma unroll
      for (int nf = 0; nf < 2; nf++)
        AO[base + nf * 16 + li] = f2bf(o[fm][nf][r] * inv);
    }
}

// ---------------------------------------------------------------------------
// Proj GEMM: out(100352x384 fp32) = AO(bf16) @ Wp^T + proj_b.  R4 structure;
// grid 2352: m=(slot/3)*8+xcd, n=slot%3.
// ---------------------------------------------------------------------------
__global__ __launch_bounds__(256) void proj_gemm(
    const float* __restrict__ proj_b, char* __restrict__ ws,
    float* __restrict__ out) {
  __shared__ unsigned short As[128][32];
  __shared__ unsigned short Bs[128][32];
  const unsigned short* AO = (const unsigned short*)(ws + OFF_AO);
  const unsigned short* Wp = (const unsigned short*)(ws + OFF_WP);
  const int L = blockIdx.x;
  const int xcd = L & 7, slot = L >> 3;
  const int g3 = slot / 3;
  const int m0 = (g3 * 8 + xcd) * 128;
  const int n0 = (slot - g3 * 3) * 128;
  const int t = threadIdx.x;
  const int lane = t & 63, li = lane & 15, qd = lane >> 4;
  const int wv = t >> 6, wm = wv >> 1, wn = wv & 1;
  const int ld_r = lane >> 2;
  const int ld_c = (lane & 3) * 8;
  const unsigned short* agp = AO + (size_t)(m0 + wv * 32 + ld_r) * CDIM + ld_c;
  const unsigned short* bgp = Wp + (size_t)(n0 + wv * 32 + ld_r) * CDIM + ld_c;
  floatx4 acc[4][4] = {};
  for (int k0 = 0; k0 < CDIM; k0 += 32) {
    gl2lds16(agp + k0,             &As[wv * 32][0]);
    gl2lds16(agp + k0 + 16 * CDIM, &As[wv * 32 + 16][0]);
    gl2lds16(bgp + k0,             &Bs[wv * 32][0]);
    gl2lds16(bgp + k0 + 16 * CDIM, &Bs[wv * 32 + 16][0]);
    __syncthreads();
    short8 a[4], b[4];
#pragma unroll
    for (int f = 0; f < 4; f++)
      a[f] = *(const short8*)&As[wm * 64 + f * 16 + li][qd * 8];
#pragma unroll
    for (int f = 0; f < 4; f++)
      b[f] = *(const short8*)&Bs[wn * 64 + f * 16 + li][qd * 8];
#pragma unroll
    for (int i = 0; i < 4; i++)
#pragma unroll
      for (int j = 0; j < 4; j++)
        acc[i][j] = __builtin_amdgcn_mfma_f32_16x16x32_bf16(a[i], b[j], acc[i][j], 0, 0, 0);
    __syncthreads();
  }
#pragma unroll
  for (int i = 0; i < 4; i++)
#pragma unroll
    for (int j = 0; j < 4; j++) {
      int c = n0 + wn * 64 + j * 16 + li;
      float bv = proj_b[c];
#pragma unroll
      for (int r = 0; r < 4; r++) {
        int m = m0 + wm * 64 + i * 16 + qd * 4 + r;
        out[(size_t)m * CDIM + c] = acc[i][j][r] + bv;
      }
    }
}

extern "C" void kernel_launch(void* const* d_in, const int* in_sizes, int n_in,
                              void* d_out, int out_size, void* d_ws, size_t ws_size,
                              hipStream_t stream) {
  const float* x      = (const float*)d_in[0];
  const float* qkv_w  = (const float*)d_in[1];
  const float* qkv_b  = (const float*)d_in[2];
  const float* proj_w = (const float*)d_in[3];
  const float* proj_b = (const float*)d_in[4];
  const float* rbt    = (const float*)d_in[5];
  char* ws = (char*)d_ws;
  float* out = (float*)d_out;

  prep_kernel<<<2048, 256, 0, stream>>>(x, qkv_w, proj_w, rbt, ws);
  qkv_gemm<<<7056, 256, 0, stream>>>(qkv_b, ws);
  attn_kernel<<<dim3(2048, 3), 256, 0, stream>>>(ws);
  proj_gemm<<<2352, 256, 0, stream>>>(proj_b, ws, out);
}